// Round 6
// baseline (1149.048 us; speedup 1.0000x reference)
//
#include <hip/hip_runtime.h>

#define HIDDEN 450
#define MAX_NB 15
#define N_ATOMS 20000
#define N_BONDS 40000
#define N_MESS  16000
#define N_MOLS  1000
#define KPAD    512     // padded concat-K: [feat 0..39 | nei 40..489 | pad]
#define MSTRIDE 456     // message row stride = 912B = 57 x 16B chunks

typedef unsigned int uint;
typedef unsigned short ushort;
typedef __bf16 bf16x8 __attribute__((ext_vector_type(8)));
typedef float  f32x4  __attribute__((ext_vector_type(4)));

__device__ __forceinline__ ushort f2bf(float f) {
    uint u = __builtin_bit_cast(uint, f);
    u += 0x7fffu + ((u >> 16) & 1u);     // RNE
    return (ushort)(u >> 16);
}
__device__ __forceinline__ float bfhi(uint w) {
    return __builtin_bit_cast(float, w & 0xffff0000u);
}
__device__ __forceinline__ float bflo(uint w) {
    return __builtin_bit_cast(float, w << 16);
}

// ---------------- pack kernels (run once per launch) ----------------

__global__ __launch_bounds__(256) void pack_tree(const float* __restrict__ tree,
                                                 ushort* __restrict__ tbuf) {
    const int r = blockIdx.x, t = threadIdx.x;
    if (t < 228) {
        uint p = 0;
        if (t < 225) {
            const float2 v = *(const float2*)&tree[(size_t)r * HIDDEN + 2 * t];
            p = (uint)f2bf(v.x) | ((uint)f2bf(v.y) << 16);
        }
        ((uint*)(tbuf + (size_t)r * MSTRIDE))[t] = p;
    }
}

__global__ __launch_bounds__(256) void pack_bonds(const float* __restrict__ fbonds,
                                                  ushort* __restrict__ Abuf) {
    const int r = blockIdx.x * 4 + (threadIdx.x >> 6);
    const int t = threadIdx.x & 63;
    if (r >= N_BONDS) return;
    ushort* row = Abuf + (size_t)r * KPAD;
    if (t < 40) row[t] = f2bf(fbonds[(size_t)r * 40 + t]);
    else        row[t] = 0;                    // cols 40..63 zero (first GEMM K=64)
    if (t < 16) row[496 + t] = 0;              // cols 496..511 zero
}

__global__ __launch_bounds__(256) void pack_atoms(const float* __restrict__ fatoms,
                                                  ushort* __restrict__ Aout) {
    const int r = blockIdx.x * 4 + (threadIdx.x >> 6);
    const int t = threadIdx.x & 63;
    if (r >= N_ATOMS) return;
    ushort* row = Aout + (size_t)r * KPAD;
    if (t < 40) row[t] = (t < 35) ? f2bf(fatoms[(size_t)r * 35 + t]) : (ushort)0;
    if (t < 16) row[496 + t] = 0;              // cols 496..511 zero
}

__global__ __launch_bounds__(256) void pack_w(const float* __restrict__ W_i,
                                              const float* __restrict__ W_h,
                                              const float* __restrict__ W_o,
                                              ushort* __restrict__ Wcat,
                                              ushort* __restrict__ Wocat) {
    const int n = blockIdx.x;  // 0..511
    for (int c = threadIdx.x; c < KPAD; c += 256) {
        float v = 0.0f, vo = 0.0f;
        if (n < HIDDEN) {
            if (c < 40)       v = W_i[(size_t)n * 40 + c];
            else if (c < 490) v = W_h[(size_t)n * HIDDEN + (c - 40)];
            if (c < 35)       vo = W_o[(size_t)n * 485 + c];
            else if (c >= 40 && c < 490) vo = W_o[(size_t)n * 485 + 35 + (c - 40)];
        }
        Wcat [(size_t)n * KPAD + c] = f2bf(v);
        Wocat[(size_t)n * KPAD + c] = f2bf(vo);
    }
}

// ---------------- gather: dst[r, 40..495] = sum_j concat(tree,gmsg)[g[r,j]] -------
__global__ __launch_bounds__(256) void gather_sum(const int* __restrict__ g,
                                                  const ushort* __restrict__ tbuf,
                                                  const ushort* __restrict__ gmsg,
                                                  ushort* __restrict__ dst, int nrows) {
    const int r = blockIdx.x * 4 + (threadIdx.x >> 6);
    const int lane = threadIdx.x & 63;
    if (r >= nrows) return;
    const int* gr = g + (size_t)r * MAX_NB;
    int idx[MAX_NB];
#pragma unroll
    for (int j = 0; j < MAX_NB; ++j) idx[j] = gr[j];
    if (lane >= 57) return;
    const int off = lane * 8;
    float acc[8] = {};
#pragma unroll
    for (int j = 0; j < MAX_NB; ++j) {
        const ushort* row = (idx[j] < N_MESS)
            ? tbuf + (size_t)idx[j] * MSTRIDE
            : gmsg + (size_t)(idx[j] - N_MESS) * MSTRIDE;
        const uint4 w = *(const uint4*)(row + off);
        acc[0] += bflo(w.x); acc[1] += bfhi(w.x);
        acc[2] += bflo(w.y); acc[3] += bfhi(w.y);
        acc[4] += bflo(w.z); acc[5] += bfhi(w.z);
        acc[6] += bflo(w.w); acc[7] += bfhi(w.w);
    }
    uint4 p;
    p.x = (uint)f2bf(acc[0]) | ((uint)f2bf(acc[1]) << 16);
    p.y = (uint)f2bf(acc[2]) | ((uint)f2bf(acc[3]) << 16);
    p.z = (uint)f2bf(acc[4]) | ((uint)f2bf(acc[5]) << 16);
    p.w = (uint)f2bf(acc[6]) | ((uint)f2bf(acc[7]) << 16);
    *(uint4*)(dst + (size_t)r * KPAD + 40 + off) = p;
}

// ---------------- MFMA GEMM: A-tile in swizzled LDS, W direct from L2 ------------
// C[M x 450] = relu(A[M x K] · W[450 x K]^T (+bias))
// Block: 512 thr / 8 waves, tile 64m x 256n (waves 2m x 4n of 32x64).
// A-tile (64 x K bf16, <=64KB) staged ONCE via VGPR + xor-swizzled ds_write;
// K-loop is barrier-free. Grid XCD-swizzled: id = b + 8*(n + 2*q), m_blk = 8q+b.
// MODE 0: bf16 store to gmsg (+ zero pad cols). MODE 1: f32 atomicAdd to out
// with equal-mol run merging (mol_ids sorted).
template <int MODE>
__global__ __launch_bounds__(512, 4) void mfma_gemm(
    const ushort* __restrict__ A, int M,
    const ushort* __restrict__ W, int K,
    const float* __restrict__ bias, const int* __restrict__ mol_ids,
    ushort* __restrict__ gout, float* __restrict__ aout, int mtiles) {
    __shared__ ushort At[64 * 512];     // 64KB; uses [64][K] region, xor-swizzled
    const int tid = threadIdx.x;
    const int id  = blockIdx.x;
    const int b     = id & 7;           // XCD residue
    const int n_blk = (id >> 3) & 1;
    const int q     = id >> 4;
    const int m_blk = q * 8 + b;
    if (m_blk >= mtiles) return;        // block-uniform early out (before barrier)
    const int m0 = m_blk * 64, n0 = n_blk * 256;
    const int cpr = K >> 3;             // 16B chunks per row

    // ---- stage A-tile: row srow, chunks (tid&7)+8i, swizzled chunk ^ (row&7) ----
    {
        const int srow = tid >> 3;
        const int c0   = tid & 7;
        const ushort* gsrc = A + (size_t)min(m0 + srow, M - 1) * KPAD;
        ushort* lrow = At + srow * cpr * 8;
#pragma unroll 2
        for (int c = c0; c < cpr; c += 8) {
            const uint4 v = *(const uint4*)(gsrc + c * 8);
            *(uint4*)&lrow[(c ^ (srow & 7)) * 8] = v;
        }
    }
    __syncthreads();                    // the ONLY barrier

    const int lane = tid & 63;
    const int wave = tid >> 6;
    const int wm = (wave >> 2) * 32;    // wave tile: 32m x 64n
    const int wn = (wave & 3) * 64;
    const int lr = lane & 15;
    const int lk = lane >> 4;

    size_t woff[4];
#pragma unroll
    for (int s = 0; s < 4; ++s)
        woff[s] = (size_t)(n0 + wn + s * 16 + lr) * KPAD + lk * 8;

    f32x4 acc[2][4];
#pragma unroll
    for (int i = 0; i < 2; ++i)
#pragma unroll
        for (int j = 0; j < 4; ++j) acc[i][j] = (f32x4){0.f, 0.f, 0.f, 0.f};

    bf16x8 w_cur[4], w_nxt[4];
#pragma unroll
    for (int s = 0; s < 4; ++s) w_cur[s] = *(const bf16x8*)&W[woff[s]];

#pragma unroll 1
    for (int k0 = 0; k0 < K; k0 += 32) {
        const int kn = (k0 + 32 < K) ? k0 + 32 : 0;   // clamped prefetch
#pragma unroll
        for (int s = 0; s < 4; ++s) w_nxt[s] = *(const bf16x8*)&W[woff[s] + kn];

        bf16x8 af[2];
#pragma unroll
        for (int mt = 0; mt < 2; ++mt) {
            const int row = wm + mt * 16 + lr;
            const int chunk = ((k0 >> 3) + lk) ^ (row & 7);
            af[mt] = *(const bf16x8*)&At[(row * cpr + chunk) * 8];
        }
#pragma unroll
        for (int mt = 0; mt < 2; ++mt)
#pragma unroll
            for (int nt = 0; nt < 4; ++nt)
                acc[mt][nt] = __builtin_amdgcn_mfma_f32_16x16x32_bf16(
                    af[mt], w_cur[nt], acc[mt][nt], 0, 0, 0);
#pragma unroll
        for (int s = 0; s < 4; ++s) w_cur[s] = w_nxt[s];
    }

    const int col_l = lane & 15;
    const int rbase = (lane >> 4) * 4;
#pragma unroll
    for (int mt = 0; mt < 2; ++mt) {
        const int mbase = m0 + wm + mt * 16 + rbase;
        int mol[4];
        if (MODE == 1) {
#pragma unroll
            for (int reg = 0; reg < 4; ++reg)
                mol[reg] = mol_ids[min(mbase + reg, M - 1)];
        }
#pragma unroll
        for (int nt = 0; nt < 4; ++nt) {
            const int n = n0 + wn + nt * 16 + col_l;
            if (MODE == 0) {
#pragma unroll
                for (int reg = 0; reg < 4; ++reg) {
                    const int m = mbase + reg;
                    if (m >= M) continue;
                    if (n < HIDDEN)
                        gout[(size_t)m * MSTRIDE + n] = f2bf(fmaxf(acc[mt][nt][reg], 0.0f));
                    else if (n < MSTRIDE)
                        gout[(size_t)m * MSTRIDE + n] = 0;   // keep pad cols zero
                }
            } else {
                if (n >= HIDDEN) continue;
                const float bsum = bias[n];
                float run = 0.0f;
                int cur = mol[0];
#pragma unroll
                for (int reg = 0; reg < 4; ++reg) {
                    const float v = (mbase + reg < M)
                        ? fmaxf(acc[mt][nt][reg] + bsum, 0.0f) : 0.0f;
                    if (mol[reg] != cur) {
                        atomicAdd(&aout[(size_t)cur * HIDDEN + n], run);
                        cur = mol[reg];
                        run = 0.0f;
                    }
                    run += v;
                }
                atomicAdd(&aout[(size_t)cur * HIDDEN + n], run);
            }
        }
    }
}

// ---------------- molecule mean ----------------
__global__ __launch_bounds__(256) void count_atoms(const int* __restrict__ mol_ids,
                                                   float* __restrict__ counts) {
    const int a = blockIdx.x * 256 + threadIdx.x;
    if (a < N_ATOMS) atomicAdd(&counts[mol_ids[a]], 1.0f);
}
__global__ __launch_bounds__(256) void div_counts(float* __restrict__ out,
                                                  const float* __restrict__ counts) {
    const int i = blockIdx.x * 256 + threadIdx.x;
    if (i < N_MOLS * HIDDEN) out[i] = out[i] / counts[i / HIDDEN];
}

extern "C" void kernel_launch(void* const* d_in, const int* in_sizes, int n_in,
                              void* d_out, int out_size, void* d_ws, size_t ws_size,
                              hipStream_t stream) {
    const float* fatoms  = (const float*)d_in[0];
    const float* fbonds  = (const float*)d_in[1];
    const int*   agraph  = (const int*)d_in[2];
    const int*   bgraph  = (const int*)d_in[3];
    const int*   mol_ids = (const int*)d_in[4];
    const float* tree    = (const float*)d_in[6];
    const float* W_i     = (const float*)d_in[7];
    const float* W_h     = (const float*)d_in[8];
    const float* W_o     = (const float*)d_in[9];
    const float* b_o     = (const float*)d_in[10];
    float* out = (float*)d_out;

    ushort* Abuf  = (ushort*)d_ws;                       // 40000 x 512
    ushort* Aout  = Abuf  + (size_t)N_BONDS * KPAD;      // 20000 x 512
    ushort* gmsg  = Aout  + (size_t)N_ATOMS * KPAD;      // 40000 x 456
    ushort* tbuf  = gmsg  + (size_t)N_BONDS * MSTRIDE;   // 16000 x 456
    ushort* Wcat  = tbuf  + (size_t)N_MESS  * MSTRIDE;   // 512 x 512
    ushort* Wocat = Wcat  + (size_t)KPAD * KPAD;         // 512 x 512
    float*  counts = (float*)(Wocat + (size_t)KPAD * KPAD);

    (void)hipMemsetAsync(d_out, 0, (size_t)N_MOLS * HIDDEN * sizeof(float), stream);
    (void)hipMemsetAsync(counts, 0, N_MOLS * sizeof(float), stream);

    const dim3 blk(256);
    pack_tree <<<N_MESS, blk, 0, stream>>>(tree, tbuf);
    pack_bonds<<<(N_BONDS + 3) / 4, blk, 0, stream>>>(fbonds, Abuf);
    pack_atoms<<<(N_ATOMS + 3) / 4, blk, 0, stream>>>(fatoms, Aout);
    pack_w    <<<KPAD, blk, 0, stream>>>(W_i, W_h, W_o, Wcat, Wocat);

    // grid: id = b + 8*(n_blk + 2*q); mtiles = ceil(M/64)
    const int mtB = (N_BONDS + 63) / 64;                 // 625
    const int mtA = (N_ATOMS + 63) / 64;                 // 313
    const dim3 gB(((mtB + 7) / 8) * 16);                 // 1264 blocks
    const dim3 gA(((mtA + 7) / 8) * 16);                 // 640 blocks
    const dim3 blk512(512);

    // gmsg = relu(fbonds @ W_i^T): nei cols 40..63 are zero, so K=64 suffices
    mfma_gemm<0><<<gB, blk512, 0, stream>>>(Abuf, N_BONDS, Wcat, 64,
                                            nullptr, nullptr, gmsg, nullptr, mtB);
    for (int it = 0; it < 5; ++it) {
        gather_sum<<<(N_BONDS + 3) / 4, blk, 0, stream>>>(bgraph, tbuf, gmsg,
                                                          Abuf, N_BONDS);
        mfma_gemm<0><<<gB, blk512, 0, stream>>>(Abuf, N_BONDS, Wcat, KPAD,
                                                nullptr, nullptr, gmsg, nullptr, mtB);
    }
    gather_sum<<<(N_ATOMS + 3) / 4, blk, 0, stream>>>(agraph, tbuf, gmsg,
                                                      Aout, N_ATOMS);
    mfma_gemm<1><<<gA, blk512, 0, stream>>>(Aout, N_ATOMS, Wocat, KPAD,
                                            b_o, mol_ids, nullptr, out, mtA);

    count_atoms<<<(N_ATOMS + 255) / 256, blk, 0, stream>>>(mol_ids, counts);
    div_counts <<<(N_MOLS * HIDDEN + 255) / 256, blk, 0, stream>>>(out, counts);
}

// Round 7
// 921.434 us; speedup vs baseline: 1.2470x; 1.2470x over previous
//
#include <hip/hip_runtime.h>

#define HIDDEN 450
#define MAX_NB 15
#define N_ATOMS 20000
#define N_BONDS 40000
#define N_MESS  16000
#define N_MOLS  1000
#define KPAD    512     // padded concat-K: [feat 0..39 | nei 40..489 | pad]
#define MSTRIDE 456     // message/base row stride = 912B = 57 x 16B chunks

typedef unsigned int uint;
typedef unsigned short ushort;
typedef __bf16 bf16x8 __attribute__((ext_vector_type(8)));
typedef float  f32x4  __attribute__((ext_vector_type(4)));

__device__ __forceinline__ ushort f2bf(float f) {
    uint u = __builtin_bit_cast(uint, f);
    u += 0x7fffu + ((u >> 16) & 1u);     // RNE
    return (ushort)(u >> 16);
}
__device__ __forceinline__ float bfhi(uint w) {
    return __builtin_bit_cast(float, w & 0xffff0000u);
}
__device__ __forceinline__ float bflo(uint w) {
    return __builtin_bit_cast(float, w << 16);
}

// ---------------- pack kernels (run once per launch) ----------------

__global__ __launch_bounds__(256) void pack_tree(const float* __restrict__ tree,
                                                 ushort* __restrict__ tbuf) {
    const int r = blockIdx.x, t = threadIdx.x;
    if (t < 228) {
        uint p = 0;
        if (t < 225) {
            const float2 v = *(const float2*)&tree[(size_t)r * HIDDEN + 2 * t];
            p = (uint)f2bf(v.x) | ((uint)f2bf(v.y) << 16);
        }
        ((uint*)(tbuf + (size_t)r * MSTRIDE))[t] = p;
    }
}

__global__ __launch_bounds__(256) void pack_bonds(const float* __restrict__ fbonds,
                                                  ushort* __restrict__ Abuf) {
    const int r = blockIdx.x * 4 + (threadIdx.x >> 6);
    const int t = threadIdx.x & 63;
    if (r >= N_BONDS) return;
    ushort* row = Abuf + (size_t)r * KPAD;
    if (t < 40) row[t] = f2bf(fbonds[(size_t)r * 40 + t]);
    else        row[t] = 0;                    // cols 40..63 zero (first GEMM K=64)
    if (t < 16) row[496 + t] = 0;              // cols 496..511 zero
}

__global__ __launch_bounds__(256) void pack_atoms(const float* __restrict__ fatoms,
                                                  ushort* __restrict__ Aout) {
    const int r = blockIdx.x * 4 + (threadIdx.x >> 6);
    const int t = threadIdx.x & 63;
    if (r >= N_ATOMS) return;
    ushort* row = Aout + (size_t)r * KPAD;
    if (t < 40) row[t] = (t < 35) ? f2bf(fatoms[(size_t)r * 35 + t]) : (ushort)0;
    if (t < 16) row[496 + t] = 0;              // cols 496..511 zero
}

__global__ __launch_bounds__(256) void pack_w(const float* __restrict__ W_i,
                                              const float* __restrict__ W_h,
                                              const float* __restrict__ W_o,
                                              ushort* __restrict__ Wcat,
                                              ushort* __restrict__ Wocat) {
    const int n = blockIdx.x;  // 0..511
    for (int c = threadIdx.x; c < KPAD; c += 256) {
        float v = 0.0f, vo = 0.0f;
        if (n < HIDDEN) {
            if (c < 40)       v = W_i[(size_t)n * 40 + c];
            else if (c < 490) v = W_h[(size_t)n * HIDDEN + (c - 40)];
            if (c < 35)       vo = W_o[(size_t)n * 485 + c];
            else if (c >= 40 && c < 490) vo = W_o[(size_t)n * 485 + 35 + (c - 40)];
        }
        Wcat [(size_t)n * KPAD + c] = f2bf(v);
        Wocat[(size_t)n * KPAD + c] = f2bf(vo);
    }
}

// ---------------- static-base precompute: base[r] = sum_{idx<N_MESS} tbuf[idx] ----
__global__ __launch_bounds__(256) void precompute_base(const int* __restrict__ g,
                                                       const ushort* __restrict__ tbuf,
                                                       ushort* __restrict__ base,
                                                       int nrows) {
    const int r = blockIdx.x * 4 + (threadIdx.x >> 6);
    const int lane = threadIdx.x & 63;
    if (r >= nrows) return;
    const int* gr = g + (size_t)r * MAX_NB;
    int idx[MAX_NB];
#pragma unroll
    for (int j = 0; j < MAX_NB; ++j) idx[j] = gr[j];
    if (lane >= 57) return;
    const int off = lane * 8;
    float acc[8] = {};
#pragma unroll
    for (int j = 0; j < MAX_NB; ++j) {
        if (idx[j] < N_MESS) {       // wave-uniform branch (idx shared per row)
            const uint4 w = *(const uint4*)(tbuf + (size_t)idx[j] * MSTRIDE + off);
            acc[0] += bflo(w.x); acc[1] += bfhi(w.x);
            acc[2] += bflo(w.y); acc[3] += bfhi(w.y);
            acc[4] += bflo(w.z); acc[5] += bfhi(w.z);
            acc[6] += bflo(w.w); acc[7] += bfhi(w.w);
        }
    }
    uint4 p;
    p.x = (uint)f2bf(acc[0]) | ((uint)f2bf(acc[1]) << 16);
    p.y = (uint)f2bf(acc[2]) | ((uint)f2bf(acc[3]) << 16);
    p.z = (uint)f2bf(acc[4]) | ((uint)f2bf(acc[5]) << 16);
    p.w = (uint)f2bf(acc[6]) | ((uint)f2bf(acc[7]) << 16);
    *(uint4*)(base + (size_t)r * MSTRIDE + off) = p;
}

// ---------------- gather: dst[r,40..495] = base[r] + sum_{idx>=N_MESS} gmsg[...] --
__global__ __launch_bounds__(256) void gather_dyn(const int* __restrict__ g,
                                                  const ushort* __restrict__ base,
                                                  const ushort* __restrict__ gmsg,
                                                  ushort* __restrict__ dst, int nrows) {
    const int r = blockIdx.x * 4 + (threadIdx.x >> 6);
    const int lane = threadIdx.x & 63;
    if (r >= nrows) return;
    const int* gr = g + (size_t)r * MAX_NB;
    int idx[MAX_NB];
#pragma unroll
    for (int j = 0; j < MAX_NB; ++j) idx[j] = gr[j];
    if (lane >= 57) return;
    const int off = lane * 8;
    const uint4 b = *(const uint4*)(base + (size_t)r * MSTRIDE + off);
    float acc[8];
    acc[0] = bflo(b.x); acc[1] = bfhi(b.x);
    acc[2] = bflo(b.y); acc[3] = bfhi(b.y);
    acc[4] = bflo(b.z); acc[5] = bfhi(b.z);
    acc[6] = bflo(b.w); acc[7] = bfhi(b.w);
#pragma unroll
    for (int j = 0; j < MAX_NB; ++j) {
        if (idx[j] >= N_MESS) {      // wave-uniform branch
            const uint4 w = *(const uint4*)(gmsg + (size_t)(idx[j] - N_MESS) * MSTRIDE + off);
            acc[0] += bflo(w.x); acc[1] += bfhi(w.x);
            acc[2] += bflo(w.y); acc[3] += bfhi(w.y);
            acc[4] += bflo(w.z); acc[5] += bfhi(w.z);
            acc[6] += bflo(w.w); acc[7] += bfhi(w.w);
        }
    }
    uint4 p;
    p.x = (uint)f2bf(acc[0]) | ((uint)f2bf(acc[1]) << 16);
    p.y = (uint)f2bf(acc[2]) | ((uint)f2bf(acc[3]) << 16);
    p.z = (uint)f2bf(acc[4]) | ((uint)f2bf(acc[5]) << 16);
    p.w = (uint)f2bf(acc[6]) | ((uint)f2bf(acc[7]) << 16);
    *(uint4*)(dst + (size_t)r * KPAD + 40 + off) = p;
}

// ---------------- MFMA GEMM v3 ----------------
// C[M x 450] = relu(A[M x K] · W[450 x K]^T (+bias)), K = KT*32.
// Block: 256 thr / 4 waves; tile 64m x 256n; wave tile 64m x 64n (msub=4,nsub=4;
// each W fragment feeds 4 MFMAs, W lines fetched once per block).
// A-tile staged ONCE in swizzled LDS; K-loop fully unrolled, barrier-free,
// W prefetch 2 steps deep, A-frag prefetch 1 step. LDS 64KB -> 2 blocks/CU.
// MODE 0: bf16 store to gmsg (+ zero pad cols). MODE 1: f32 atomicAdd w/ run-merge.
template <int MODE, int KT>
__global__ __launch_bounds__(256, 2) void mfma_gemm(
    const ushort* __restrict__ A, int M,
    const ushort* __restrict__ W,
    const float* __restrict__ bias, const int* __restrict__ mol_ids,
    ushort* __restrict__ gout, float* __restrict__ aout, int mtiles) {
    __shared__ ushort At[64 * KT * 32];     // KT=16 -> 64KB
    const int tid = threadIdx.x;
    const int id  = blockIdx.x;
    const int b     = id & 7;               // XCD residue
    const int n_blk = (id >> 3) & 1;
    const int m_blk = (id >> 4) * 8 + b;
    if (m_blk >= mtiles) return;            // uniform early-out (before barrier)
    const int m0 = m_blk * 64, n0 = n_blk * 256;
    const int CPR = KT * 4;                 // 16B chunks per LDS row

    // ---- stage A-tile once: 64 rows x CPR chunks, chunk ^ (row&7) swizzle ----
    {
        const int srow = tid >> 2;
        const int c0   = tid & 3;
        const ushort* gsrc = A + (size_t)min(m0 + srow, M - 1) * KPAD;
        ushort* lrow = At + srow * (KT * 32);
#pragma unroll
        for (int c = c0; c < CPR; c += 4) {
            const uint4 v = *(const uint4*)(gsrc + c * 8);
            *(uint4*)&lrow[(c ^ (srow & 7)) * 8] = v;
        }
    }
    __syncthreads();                        // the ONLY barrier

    const int lane = tid & 63;
    const int wave = tid >> 6;
    const int wn = wave * 64;               // wave tile: 64m x 64n
    const int lr = lane & 15;
    const int lk = lane >> 4;

    size_t woff[4];
#pragma unroll
    for (int s = 0; s < 4; ++s)
        woff[s] = (size_t)(n0 + wn + s * 16 + lr) * KPAD + lk * 8;

    f32x4 acc[4][4];
#pragma unroll
    for (int i = 0; i < 4; ++i)
#pragma unroll
        for (int j = 0; j < 4; ++j) acc[i][j] = (f32x4){0.f, 0.f, 0.f, 0.f};

    // W pipeline: wa = step i, wb = step i+1; A pipeline: afa = step i
    bf16x8 wa[4], wb[4], afa[4];
#pragma unroll
    for (int s = 0; s < 4; ++s) wa[s] = *(const bf16x8*)&W[woff[s]];
#pragma unroll
    for (int s = 0; s < 4; ++s)
        wb[s] = (KT > 1) ? *(const bf16x8*)&W[woff[s] + 32] : wa[s];
#pragma unroll
    for (int mt = 0; mt < 4; ++mt) {
        const int row = mt * 16 + lr;
        afa[mt] = *(const bf16x8*)&At[(row * CPR + (lk ^ (row & 7))) * 8];
    }

#pragma unroll
    for (int i = 0; i < KT; ++i) {
        bf16x8 wc[4], afb[4];
        if (i + 2 < KT) {
#pragma unroll
            for (int s = 0; s < 4; ++s)
                wc[s] = *(const bf16x8*)&W[woff[s] + (size_t)(i + 2) * 32];
        }
        if (i + 1 < KT) {
#pragma unroll
            for (int mt = 0; mt < 4; ++mt) {
                const int row = mt * 16 + lr;
                const int chunk = (((i + 1) * 4 + lk)) ^ (row & 7);
                afb[mt] = *(const bf16x8*)&At[(row * CPR + chunk) * 8];
            }
        }
#pragma unroll
        for (int mt = 0; mt < 4; ++mt)
#pragma unroll
            for (int nt = 0; nt < 4; ++nt)
                acc[mt][nt] = __builtin_amdgcn_mfma_f32_16x16x32_bf16(
                    afa[mt], wa[nt], acc[mt][nt], 0, 0, 0);
        if (i + 1 < KT) {
#pragma unroll
            for (int s = 0; s < 4; ++s) wa[s] = wb[s];
#pragma unroll
            for (int mt = 0; mt < 4; ++mt) afa[mt] = afb[mt];
        }
        if (i + 2 < KT) {
#pragma unroll
            for (int s = 0; s < 4; ++s) wb[s] = wc[s];
        }
    }

    const int col_l = lane & 15;
    const int rbase = (lane >> 4) * 4;
#pragma unroll
    for (int mt = 0; mt < 4; ++mt) {
        const int mbase = m0 + mt * 16 + rbase;
        int mol[4];
        if (MODE == 1) {
#pragma unroll
            for (int reg = 0; reg < 4; ++reg)
                mol[reg] = mol_ids[min(mbase + reg, M - 1)];
        }
#pragma unroll
        for (int nt = 0; nt < 4; ++nt) {
            const int n = n0 + wn + nt * 16 + col_l;
            if (MODE == 0) {
#pragma unroll
                for (int reg = 0; reg < 4; ++reg) {
                    const int m = mbase + reg;
                    if (m >= M) continue;
                    if (n < HIDDEN)
                        gout[(size_t)m * MSTRIDE + n] = f2bf(fmaxf(acc[mt][nt][reg], 0.0f));
                    else if (n < MSTRIDE)
                        gout[(size_t)m * MSTRIDE + n] = 0;   // keep pad cols zero
                }
            } else {
                if (n >= HIDDEN) continue;
                const float bsum = bias[n];
                float run = 0.0f;
                int cur = mol[0];
#pragma unroll
                for (int reg = 0; reg < 4; ++reg) {
                    const float v = (mbase + reg < M)
                        ? fmaxf(acc[mt][nt][reg] + bsum, 0.0f) : 0.0f;
                    if (mol[reg] != cur) {
                        atomicAdd(&aout[(size_t)cur * HIDDEN + n], run);
                        cur = mol[reg];
                        run = 0.0f;
                    }
                    run += v;
                }
                atomicAdd(&aout[(size_t)cur * HIDDEN + n], run);
            }
        }
    }
}

// ---------------- molecule mean ----------------
__global__ __launch_bounds__(256) void count_atoms(const int* __restrict__ mol_ids,
                                                   float* __restrict__ counts) {
    const int a = blockIdx.x * 256 + threadIdx.x;
    if (a < N_ATOMS) atomicAdd(&counts[mol_ids[a]], 1.0f);
}
__global__ __launch_bounds__(256) void div_counts(float* __restrict__ out,
                                                  const float* __restrict__ counts) {
    const int i = blockIdx.x * 256 + threadIdx.x;
    if (i < N_MOLS * HIDDEN) out[i] = out[i] / counts[i / HIDDEN];
}

extern "C" void kernel_launch(void* const* d_in, const int* in_sizes, int n_in,
                              void* d_out, int out_size, void* d_ws, size_t ws_size,
                              hipStream_t stream) {
    const float* fatoms  = (const float*)d_in[0];
    const float* fbonds  = (const float*)d_in[1];
    const int*   agraph  = (const int*)d_in[2];
    const int*   bgraph  = (const int*)d_in[3];
    const int*   mol_ids = (const int*)d_in[4];
    const float* tree    = (const float*)d_in[6];
    const float* W_i     = (const float*)d_in[7];
    const float* W_h     = (const float*)d_in[8];
    const float* W_o     = (const float*)d_in[9];
    const float* b_o     = (const float*)d_in[10];
    float* out = (float*)d_out;

    ushort* Abuf   = (ushort*)d_ws;                        // 40000 x 512
    ushort* Aout   = Abuf   + (size_t)N_BONDS * KPAD;      // 20000 x 512
    ushort* gmsg   = Aout   + (size_t)N_ATOMS * KPAD;      // 40000 x 456
    ushort* tbuf   = gmsg   + (size_t)N_BONDS * MSTRIDE;   // 16000 x 456
    ushort* Wcat   = tbuf   + (size_t)N_MESS  * MSTRIDE;   // 512 x 512
    ushort* Wocat  = Wcat   + (size_t)KPAD * KPAD;         // 512 x 512
    ushort* base_b = Wocat  + (size_t)KPAD * KPAD;         // 40000 x 456
    ushort* base_a = base_b + (size_t)N_BONDS * MSTRIDE;   // 20000 x 456
    float*  counts = (float*)(base_a + (size_t)N_ATOMS * MSTRIDE);

    (void)hipMemsetAsync(d_out, 0, (size_t)N_MOLS * HIDDEN * sizeof(float), stream);
    (void)hipMemsetAsync(counts, 0, N_MOLS * sizeof(float), stream);

    const dim3 blk(256);
    pack_tree <<<N_MESS, blk, 0, stream>>>(tree, tbuf);
    pack_bonds<<<(N_BONDS + 3) / 4, blk, 0, stream>>>(fbonds, Abuf);
    pack_atoms<<<(N_ATOMS + 3) / 4, blk, 0, stream>>>(fatoms, Aout);
    pack_w    <<<KPAD, blk, 0, stream>>>(W_i, W_h, W_o, Wcat, Wocat);
    precompute_base<<<(N_BONDS + 3) / 4, blk, 0, stream>>>(bgraph, tbuf, base_b, N_BONDS);
    precompute_base<<<(N_ATOMS + 3) / 4, blk, 0, stream>>>(agraph, tbuf, base_a, N_ATOMS);

    // grid: id = b + 8*(n_blk + 2*q); mtiles = ceil(M/64)
    const int mtB = (N_BONDS + 63) / 64;                 // 625
    const int mtA = (N_ATOMS + 63) / 64;                 // 313
    const dim3 gB(((mtB + 7) / 8) * 16);                 // 1264
    const dim3 gA(((mtA + 7) / 8) * 16);                 // 640

    // gmsg = relu(fbonds @ W_i^T): nei cols 40..63 zero, so K=64 suffices
    mfma_gemm<0, 2><<<gB, blk, 0, stream>>>(Abuf, N_BONDS, Wcat,
                                            nullptr, nullptr, gmsg, nullptr, mtB);
    for (int it = 0; it < 5; ++it) {
        gather_dyn<<<(N_BONDS + 3) / 4, blk, 0, stream>>>(bgraph, base_b, gmsg,
                                                          Abuf, N_BONDS);
        mfma_gemm<0, 16><<<gB, blk, 0, stream>>>(Abuf, N_BONDS, Wcat,
                                                 nullptr, nullptr, gmsg, nullptr, mtB);
    }
    gather_dyn<<<(N_ATOMS + 3) / 4, blk, 0, stream>>>(agraph, base_a, gmsg,
                                                      Aout, N_ATOMS);
    mfma_gemm<1, 16><<<gA, blk, 0, stream>>>(Aout, N_ATOMS, Wocat,
                                             b_o, mol_ids, nullptr, out, mtA);

    count_atoms<<<(N_ATOMS + 255) / 256, blk, 0, stream>>>(mol_ids, counts);
    div_counts <<<(N_MOLS * HIDDEN + 255) / 256, blk, 0, stream>>>(out, counts);
}